// Round 1
// baseline (234.112 us; speedup 1.0000x reference)
//
#include <hip/hip_runtime.h>
#include <math.h>

#define ALPHA 0.7f
#define EPSF  1e-7f

// focal element: pt = pos ? p : 1-p; lg = -log(pt) (inf -> 1e-7);
// f = (1-pt)^2 * lg; pos gets * ALPHA
__device__ __forceinline__ float focal_elem(float p, int y) {
    const bool pos = (y == 1);
    const float pt = pos ? p : 1.0f - p;
    float lg = -logf(pt);
    if (isinf(lg)) lg = EPSF;
    const float om = 1.0f - pt;
    float f = om * om * lg;
    return pos ? f * ALPHA : f;
}

template <int BLOCK>
__device__ __forceinline__ float block_reduce(float acc) {
    // wave-64 shuffle reduce
    #pragma unroll
    for (int off = 32; off > 0; off >>= 1)
        acc += __shfl_down(acc, off, 64);
    __shared__ float smem[BLOCK / 64];
    const int lane = threadIdx.x & 63;
    const int wave = threadIdx.x >> 6;
    if (lane == 0) smem[wave] = acc;
    __syncthreads();
    float s = 0.0f;
    if (threadIdx.x == 0) {
        #pragma unroll
        for (int w = 0; w < BLOCK / 64; ++w) s += smem[w];
    }
    return s;
}

template <int BLOCK>
__global__ void __launch_bounds__(BLOCK)
focal_partial(const float* __restrict__ p, const int* __restrict__ y,
              float* __restrict__ partial, long long n) {
    const long long n4 = n >> 2;
    const float4* __restrict__ p4 = (const float4*)p;
    const int4*   __restrict__ y4 = (const int4*)y;
    const long long stride = (long long)gridDim.x * BLOCK;
    long long i = (long long)blockIdx.x * BLOCK + threadIdx.x;

    float acc = 0.0f;
    for (; i < n4; i += stride) {
        const float4 pv = p4[i];
        const int4   yv = y4[i];
        acc += focal_elem(pv.x, yv.x);
        acc += focal_elem(pv.y, yv.y);
        acc += focal_elem(pv.z, yv.z);
        acc += focal_elem(pv.w, yv.w);
    }
    // scalar tail (n not multiple of 4)
    const long long tail = n4 << 2;
    for (long long j = tail + (long long)blockIdx.x * BLOCK + threadIdx.x; j < n; j += stride)
        acc += focal_elem(p[j], y[j]);

    const float s = block_reduce<BLOCK>(acc);
    if (threadIdx.x == 0) partial[blockIdx.x] = s;
}

template <int BLOCK>
__global__ void __launch_bounds__(BLOCK)
focal_final(const float* __restrict__ partial, int nparts,
            float* __restrict__ out, long long n) {
    float acc = 0.0f;
    for (int i = threadIdx.x; i < nparts; i += BLOCK) acc += partial[i];
    const float s = block_reduce<BLOCK>(acc);
    if (threadIdx.x == 0) out[0] = s / (float)n;
}

extern "C" void kernel_launch(void* const* d_in, const int* in_sizes, int n_in,
                              void* d_out, int out_size, void* d_ws, size_t ws_size,
                              hipStream_t stream) {
    const float* p = (const float*)d_in[0];
    const int*   y = (const int*)d_in[1];
    float* out = (float*)d_out;
    float* partial = (float*)d_ws;

    const long long n = (long long)in_sizes[0];
    constexpr int BLOCK = 256;
    constexpr int NBLOCKS = 1024;  // 256K threads; ~27 float4 iters/thread at n=28.3M

    focal_partial<BLOCK><<<NBLOCKS, BLOCK, 0, stream>>>(p, y, partial, n);
    focal_final<BLOCK><<<1, BLOCK, 0, stream>>>(partial, NBLOCKS, out, n);
}